// Round 6
// baseline (374.325 us; speedup 1.0000x reference)
//
#include <hip/hip_runtime.h>
#include <cstdint>
#include <cstddef>

typedef unsigned short u16;
typedef __attribute__((ext_vector_type(8))) short short8;      // 8 bf16 (4 VGPRs) MFMA operand
typedef __attribute__((ext_vector_type(4))) float f32x4;       // MFMA 16x16 accumulator
typedef __attribute__((ext_vector_type(4))) float float4v;
typedef __attribute__((ext_vector_type(4))) unsigned short us4;

#define NEMBD 1024
#define NHEADS 16
#define HDIM 64
#define BB 8
#define LL 1024
#define MTOT (BB * LL)

// ---- ws layout (u16 offsets) ----
#define OFF_W 0                       // 4 weight matrices, 1<<20 u16 each (Wq,Wk,Wv,Wp)
#define OFF_B (4u << 20)              // 4 biases, 1024 u16 each (bq,bk,bv,bp)
#define OFF_QB (OFF_B + 4096)         // Q projection / attn output, 1<<23 u16
#define OFF_X (OFF_QB + (1u << 23))   // optional bf16 copies of query,key,value
#define WS_NEED_PRE ((size_t)(OFF_X + 3u * (1u << 23)) * 2)  // 75,505,664 B

static __device__ __forceinline__ float bf2f(u16 h) {
    union { unsigned u; float f; } x; x.u = ((unsigned)h) << 16; return x.f;
}
static __device__ __forceinline__ u16 f2bf(float f) {
    union { unsigned u; float f; } x; x.f = f;
    unsigned u = x.u; u += 0x7fffu + ((u >> 16) & 1u);
    return (u16)(u >> 16);
}

// async global->LDS, 16B per lane; LDS dest = wave-uniform base + lane*16
static __device__ __forceinline__ void async_ld16(const void* g, void* lds_base) {
    __builtin_amdgcn_global_load_lds(
        (const __attribute__((address_space(1))) unsigned int*)g,
        (__attribute__((address_space(3))) unsigned int*)lds_base, 16, 0, 0);
}
#define WAIT_ALL() asm volatile("s_waitcnt vmcnt(0) lgkmcnt(0)" ::: "memory")

// ------------------------------------------------------------------
// fp32 -> bf16 conversion pass (1024 elems per block).
__global__ __launch_bounds__(256) void cvt_all(
    const float* __restrict__ Wq, const float* __restrict__ Wk,
    const float* __restrict__ Wv, const float* __restrict__ Wp,
    const float* __restrict__ bq, const float* __restrict__ bk,
    const float* __restrict__ bv, const float* __restrict__ bp,
    const float* __restrict__ xq, const float* __restrict__ xk,
    const float* __restrict__ xv, u16* __restrict__ ws)
{
    int blk = blockIdx.x;
    const float* src; u16* dst; float scale = 1.f;
    if (blk < 1024)      { src = Wq; dst = ws + OFF_W;               scale = 0.125f; }
    else if (blk < 2048) { src = Wk; dst = ws + OFF_W + (1u << 20);  blk -= 1024; }
    else if (blk < 3072) { src = Wv; dst = ws + OFF_W + (2u << 20);  blk -= 2048; }
    else if (blk < 4096) { src = Wp; dst = ws + OFF_W + (3u << 20);  blk -= 3072; }
    else if (blk < 4100) {
        int wb = blk - 4096;
        src = (wb == 0) ? bq : (wb == 1) ? bk : (wb == 2) ? bv : bp;
        dst = ws + OFF_B + wb * 1024; scale = (wb == 0) ? 0.125f : 1.f; blk = 0;
    }
    else if (blk < 12292) { src = xq; dst = ws + OFF_X;               blk -= 4100; }
    else if (blk < 20484) { src = xk; dst = ws + OFF_X + (1u << 23);  blk -= 12292; }
    else                  { src = xv; dst = ws + OFF_X + (2u << 23);  blk -= 20484; }
    const int i = blk * 1024 + threadIdx.x * 4;
    float4v f = *(const float4v*)&src[i];
    us4 o;
#pragma unroll
    for (int j = 0; j < 4; j++) o[j] = f2bf(f[j] * scale);
    *(us4*)&dst[i] = o;
}

// ------------------------------------------------------------------
// Y[m][n] = sum_k X[m][k]*W[n][k] + bias[n]. M=8192, N=K=1024. BK=64,
// XOR-8 chunk swizzle on As/Bs (chunk c of row r stored at c^(r&7)).
// vtrans: write V^T layout [b][h][d][key].
template <typename TX, typename TY>
static __device__ __forceinline__ void gemm_body64(
    const TX* __restrict__ X, const u16* __restrict__ W,
    const u16* __restrict__ bias, TY* __restrict__ Y, int vtrans,
    u16* As, u16* Bs)   // each 128*64 u16
{
    constexpr int K = NEMBD, N = NEMBD;
    const int t = threadIdx.x;
    const int wave = t >> 6, lane = t & 63;
    const int quad = lane >> 4, l16 = lane & 15;
    const int m0 = blockIdx.y * 128, n0 = blockIdx.x * 128;
    const int wm = (wave >> 1) * 64, wn = (wave & 1) * 64;
    const int rsub = lane >> 3;                 // staging row within 8-row group
    const int csw = ((lane & 7) ^ rsub) * 8;    // swizzled source col (u16)
    const int swr = l16 & 7;                    // read swizzle key (row&7 == l16&7)
    const int frow = t >> 1, fc0 = (t & 1) * 4; // fp32 manual staging

    f32x4 acc[4][4];
#pragma unroll
    for (int i = 0; i < 4; i++)
#pragma unroll
        for (int j = 0; j < 4; j++) acc[i][j] = (f32x4){0.f, 0.f, 0.f, 0.f};

    for (int k0 = 0; k0 < K; k0 += 64) {
        if constexpr (__is_same(TX, u16)) {
#pragma unroll
            for (int j = 0; j < 4; j++) {
                const int g = wave * 4 + j;     // 8-row group
                async_ld16(X + (size_t)(m0 + g * 8 + rsub) * K + k0 + csw, &As[g * 8 * 64]);
            }
        } else {
#pragma unroll
            for (int c = 0; c < 4; c++) {
                const int lc = fc0 + c;
                float4v f0 = *(const float4v*)&X[(size_t)(m0 + frow) * K + k0 + lc * 8];
                float4v f1 = *(const float4v*)&X[(size_t)(m0 + frow) * K + k0 + lc * 8 + 4];
                __align__(16) u16 tmp[8];
#pragma unroll
                for (int j = 0; j < 4; j++) { tmp[j] = f2bf(f0[j]); tmp[4 + j] = f2bf(f1[j]); }
                *(short8*)&As[frow * 64 + (lc ^ (frow & 7)) * 8] = *(const short8*)tmp;
            }
        }
#pragma unroll
        for (int j = 0; j < 4; j++) {
            const int g = wave * 4 + j;
            async_ld16(W + (size_t)(n0 + g * 8 + rsub) * K + k0 + csw, &Bs[g * 8 * 64]);
        }
        WAIT_ALL();
        __syncthreads();

#pragma unroll
        for (int h = 0; h < 2; h++) {           // two 32-wide k-halves
            short8 a[4], b[4];
#pragma unroll
            for (int i = 0; i < 4; i++) {
                a[i] = *(const short8*)&As[(wm + i * 16 + l16) * 64 + (((h * 4 + quad) ^ swr) * 8)];
                b[i] = *(const short8*)&Bs[(wn + i * 16 + l16) * 64 + (((h * 4 + quad) ^ swr) * 8)];
            }
#pragma unroll
            for (int i = 0; i < 4; i++)
#pragma unroll
                for (int j = 0; j < 4; j++)
                    acc[i][j] = __builtin_amdgcn_mfma_f32_16x16x32_bf16(a[i], b[j], acc[i][j], 0, 0, 0);
        }
        __syncthreads();
    }

    // C/D layout: col=lane&15, row=quad*4+reg
    if (vtrans) {
        u16* VT = (u16*)Y;
#pragma unroll
        for (int j = 0; j < 4; j++) {
            const int n = n0 + wn + j * 16 + l16;
            const float bn = bf2f(bias[n]);
            const int h = n >> 6, d = n & 63;
#pragma unroll
            for (int i = 0; i < 4; i++) {
                const int mb = m0 + wm + i * 16 + quad * 4;
                const int b = mb >> 10, key = mb & 1023;
                us4 pack;
#pragma unroll
                for (int r = 0; r < 4; r++) pack[r] = f2bf(acc[i][j][r] + bn);
                *(us4*)&VT[(size_t)(b * 16 + h) * 65536 + d * 1024 + key] = pack;
            }
        }
    } else {
#pragma unroll
        for (int j = 0; j < 4; j++) {
            const int n = n0 + wn + j * 16 + l16;
            const float bn = bf2f(bias[n]);
#pragma unroll
            for (int i = 0; i < 4; i++) {
                const int mb = m0 + wm + i * 16 + quad * 4;
#pragma unroll
                for (int r = 0; r < 4; r++) {
                    float v = acc[i][j][r] + bn;
                    if constexpr (__is_same(TY, u16)) Y[(size_t)(mb + r) * N + n] = f2bf(v);
                    else                              Y[(size_t)(mb + r) * N + n] = v;
                }
            }
        }
    }
}

// QKV, bf16-X path. z: 0=Q->qb (pre-scaled W), 1=K->kb, 2=V->vtg (transposed)
__global__ __launch_bounds__(256) void gemm_qkv_b(
    const u16* __restrict__ xq, const u16* __restrict__ xk, const u16* __restrict__ xv,
    const u16* __restrict__ ws, u16* __restrict__ qb, u16* __restrict__ kb,
    u16* __restrict__ vtg)
{
    __shared__ __align__(16) u16 As[128 * 64];
    __shared__ __align__(16) u16 Bs[128 * 64];
    const int z = blockIdx.z;
    const u16* X = (z == 0) ? xq : (z == 1) ? xk : xv;
    const u16* W = ws + OFF_W + (size_t)z * (1u << 20);
    const u16* bias = ws + OFF_B + z * 1024;
    u16* Y = (z == 0) ? qb : (z == 1) ? kb : vtg;
    gemm_body64<u16, u16>(X, W, bias, Y, z == 2 ? 1 : 0, As, Bs);
}

// QKV, fp32-X fallback (in-GEMM convert)
__global__ __launch_bounds__(256) void gemm_qkv_f(
    const float* __restrict__ xq, const float* __restrict__ xk, const float* __restrict__ xv,
    const u16* __restrict__ ws, u16* __restrict__ qb, u16* __restrict__ kb,
    u16* __restrict__ vtg)
{
    __shared__ __align__(16) u16 As[128 * 64];
    __shared__ __align__(16) u16 Bs[128 * 64];
    const int z = blockIdx.z;
    const float* X = (z == 0) ? xq : (z == 1) ? xk : xv;
    const u16* W = ws + OFF_W + (size_t)z * (1u << 20);
    const u16* bias = ws + OFF_B + z * 1024;
    u16* Y = (z == 0) ? qb : (z == 1) ? kb : vtg;
    gemm_body64<float, u16>(X, W, bias, Y, z == 2 ? 1 : 0, As, Bs);
}

// Output projection: bf16 X, fp32 output
__global__ __launch_bounds__(256) void gemm_out_k(
    const u16* __restrict__ X, const u16* __restrict__ ws, float* __restrict__ Y)
{
    __shared__ __align__(16) u16 As[128 * 64];
    __shared__ __align__(16) u16 Bs[128 * 64];
    gemm_body64<u16, float>(X, ws + OFF_W + (size_t)3 * (1u << 20), ws + OFF_B + 3 * 1024,
                            Y, 0, As, Bs);
}

// ------------------------------------------------------------------
// Flash attention v5: BARRIER-FREE. Each wave owns 32 queries; K and V^T
// fragments are read directly from global (L2-resident: 256 KB per (b,h)),
// so there is no LDS staging and no __syncthreads. Only LDS use is the
// wave-private P transpose round-trip (lgkmcnt-only wait).
// No-max softmax (Q pre-scaled by 1/8 via Wq; scores bounded), deferred row-sums.
// Yp may alias Qp (wave reads its Q rows into registers before writing same rows).
__global__ __launch_bounds__(256, 4) void attn_fused(
    const u16* __restrict__ Qp, const u16* __restrict__ Kp,
    const u16* __restrict__ Vtg, u16* __restrict__ Yp)
{
    __shared__ __align__(16) u16 Pl[4 * 32 * 72];   // per-wave P [q][key], pad-72

    const int t = threadIdx.x;
    const int wave = t >> 6, lane = t & 63;
    const int quad = lane >> 4, l16 = lane & 15;
    const int bh = blockIdx.y;
    const int b = bh >> 4, h = bh & 15;
    const int q0w = blockIdx.x * 128 + wave * 32;   // this wave's 32 queries

    const u16* Qb = Qp + (size_t)b * LL * NEMBD + h * HDIM;
    const u16* Kb = Kp + (size_t)b * LL * NEMBD + h * HDIM;
    const u16* Vb = Vtg + (size_t)bh * 65536;       // V^T [d][key]

    // Q A-frags: [mtile][khalf], A[m=l16][k=quad*8+j]
    short8 aq[2][2];
#pragma unroll
    for (int m = 0; m < 2; m++) {
        aq[m][0] = *(const short8*)(Qb + (size_t)(q0w + m * 16 + l16) * NEMBD + quad * 8);
        aq[m][1] = *(const short8*)(Qb + (size_t)(q0w + m * 16 + l16) * NEMBD + 32 + quad * 8);
    }

    f32x4 acc[2][4];
#pragma unroll
    for (int m = 0; m < 2; m++)
#pragma unroll
        for (int n = 0; n < 4; n++) acc[m][n] = (f32x4){0.f, 0.f, 0.f, 0.f};
    float lsum[2][4] = {{0.f, 0.f, 0.f, 0.f}, {0.f, 0.f, 0.f, 0.f}};

    u16* pw = &Pl[wave * 32 * 72];
    const int ktiles = (q0w + 95) >> 6;             // keys 0..q0w+31 in 64-key tiles

    for (int kt = 0; kt < ktiles; kt++) {
        const int kbase = kt * 64;
        // ---- S = Q K^T: B-operand rows straight from global K
#pragma unroll
        for (int s = 0; s < 4; s++) {
            const u16* krow = Kb + (size_t)(kbase + s * 16 + l16) * NEMBD;
            const short8 bk0 = *(const short8*)(krow + quad * 8);
            const short8 bk1 = *(const short8*)(krow + 32 + quad * 8);
#pragma unroll
            for (int m = 0; m < 2; m++) {
                const int qlo = q0w + m * 16;
                f32x4 ss = (f32x4){0.f, 0.f, 0.f, 0.f};
                ss = __builtin_amdgcn_mfma_f32_16x16x32_bf16(aq[m][0], bk0, ss, 0, 0, 0);
                ss = __builtin_amdgcn_mfma_f32_16x16x32_bf16(aq[m][1], bk1, ss, 0, 0, 0);
                const bool diag = (kbase + 63 > qlo);
#pragma unroll
                for (int r = 0; r < 4; r++) {
                    float e = __expf(ss[r]);
                    if (diag && (kbase + s * 16 + l16 > qlo + quad * 4 + r)) e = 0.f;
                    lsum[m][r] += e;
                    pw[(m * 16 + quad * 4 + r) * 72 + s * 16 + l16] = f2bf(e);
                }
            }
        }
        asm volatile("s_waitcnt lgkmcnt(0)" ::: "memory");  // wave-private P write->read

        // ---- PV: A = P from LDS, B = V^T rows straight from global
        short8 ap[2][2];
#pragma unroll
        for (int m = 0; m < 2; m++) {
            ap[m][0] = *(const short8*)&pw[(m * 16 + l16) * 72 + quad * 8];
            ap[m][1] = *(const short8*)&pw[(m * 16 + l16) * 72 + 32 + quad * 8];
        }
#pragma unroll
        for (int n = 0; n < 4; n++) {
            const u16* vrow = Vb + (size_t)(n * 16 + l16) * LL + kbase;
            const short8 bv0 = *(const short8*)(vrow + quad * 8);
            const short8 bv1 = *(const short8*)(vrow + 32 + quad * 8);
#pragma unroll
            for (int m = 0; m < 2; m++) {
                acc[m][n] = __builtin_amdgcn_mfma_f32_16x16x32_bf16(ap[m][0], bv0, acc[m][n], 0, 0, 0);
                acc[m][n] = __builtin_amdgcn_mfma_f32_16x16x32_bf16(ap[m][1], bv1, acc[m][n], 0, 0, 0);
            }
        }
        // no barrier: Pl is wave-private, K/V come from global
    }

    u16* Yb = Yp + (size_t)b * LL * NEMBD + h * HDIM;
#pragma unroll
    for (int m = 0; m < 2; m++) {
#pragma unroll
        for (int r = 0; r < 4; r++) {
            float lr = lsum[m][r];
            lr += __shfl_xor(lr, 1); lr += __shfl_xor(lr, 2);
            lr += __shfl_xor(lr, 4); lr += __shfl_xor(lr, 8);
            const float inv = 1.f / lr;
            const int q = q0w + m * 16 + quad * 4 + r;
#pragma unroll
            for (int n = 0; n < 4; n++)
                Yb[(size_t)q * NEMBD + n * 16 + l16] = f2bf(acc[m][n][r] * inv);
        }
    }
}

// ------------------------------------------------------------------
extern "C" void kernel_launch(void* const* d_in, const int* in_sizes, int n_in,
                              void* d_out, int out_size, void* d_ws, size_t ws_size,
                              hipStream_t stream)
{
    const float* key   = (const float*)d_in[0];
    const float* value = (const float*)d_in[1];
    const float* query = (const float*)d_in[2];
    const float* Wk = (const float*)d_in[3];
    const float* bk = (const float*)d_in[4];
    const float* Wq = (const float*)d_in[5];
    const float* bq = (const float*)d_in[6];
    const float* Wv = (const float*)d_in[7];
    const float* bv = (const float*)d_in[8];
    const float* Wp = (const float*)d_in[9];
    const float* bp = (const float*)d_in[10];

    u16* ws = (u16*)d_ws;
    u16* qb = ws + OFF_QB;                       // Q proj; also attn output (alias-safe)
    u16* kb = (u16*)d_out;                       // K proj in d_out
    u16* vtg = (u16*)d_out + (1u << 23);         // V^T [b][h][d][key] in d_out

    const bool preX = ws_size >= WS_NEED_PRE;    // constant across calls -> graph-safe

    cvt_all<<<preX ? 28676 : 4100, 256, 0, stream>>>(
        Wq, Wk, Wv, Wp, bq, bk, bv, bp, query, key, value, ws);

    if (preX) {
        const u16* xq = ws + OFF_X;
        const u16* xk = ws + OFF_X + (1u << 23);
        const u16* xv = ws + OFF_X + (2u << 23);
        gemm_qkv_b<<<dim3(8, 64, 3), 256, 0, stream>>>(xq, xk, xv, ws, qb, kb, vtg);
    } else {
        gemm_qkv_f<<<dim3(8, 64, 3), 256, 0, stream>>>(query, key, value, ws, qb, kb, vtg);
    }

    attn_fused<<<dim3(8, 128), 256, 0, stream>>>(qb, kb, vtg, qb);

    gemm_out_k<<<dim3(8, 64), 256, 0, stream>>>(qb, ws, (float*)d_out);
}